// Round 1
// baseline (676.032 us; speedup 1.0000x reference)
//
#include <hip/hip_runtime.h>
#include <math.h>

#define N_NODES 100000
#define N_EDGES 3200000
#define EPS_F 1e-6f

// ws layout (floats):
//   [0]  : int flag (1 = edge_index is int32, 0 = int64)
//   [1]  : sum(p0)      [2] : sum(p1)
//   [3]  : sum(p0^2)    [4] : sum(p1^2)
//   [5]  : sum(node_sum^2)
//   [64..64+N_NODES) : node_sum (byte offset 256)
#define WS_NODE_OFF 64
#define WS_ZERO_BYTES (256 + N_NODES * sizeof(float))

__global__ void detect_idx_kernel(const int* __restrict__ idx, int* __restrict__ flag) {
    if (threadIdx.x == 0 && blockIdx.x == 0) {
        int any = 0;
        // If layout is int64 (little-endian, values in [0, 2^31)), every odd
        // 32-bit word is the zero hi-half. If layout is int32, odd words are
        // random node ids — 16 consecutive zeros is impossible in practice.
        #pragma unroll
        for (int k = 1; k < 32; k += 2) any |= idx[k];
        *flag = (any != 0) ? 1 : 0;
    }
}

__device__ __forceinline__ float wave_reduce(float v) {
    #pragma unroll
    for (int off = 32; off > 0; off >>= 1) v += __shfl_down(v, off, 64);
    return v;
}

__global__ __launch_bounds__(256) void edge_kernel(
    const float*  __restrict__ nf,      // node_features [N_NODES,4]
    const void*   __restrict__ eidx,    // edge_index [2, N_EDGES], int32 or int64
    const float*  __restrict__ logits,  // [N_EDGES]
    const float2* __restrict__ params,  // [N_EDGES, 2]
    float*        __restrict__ ws)
{
    const int flag = ((const int*)ws)[0];
    float* node_sum = ws + WS_NODE_OFF;
    float* acc = ws + 1;
    const int*       i32 = (const int*)eidx;
    const long long* i64 = (const long long*)eidx;

    float s0 = 0.f, s1 = 0.f, q0 = 0.f, q1 = 0.f;
    const int tid    = blockIdx.x * blockDim.x + threadIdx.x;
    const int stride = gridDim.x * blockDim.x;

    for (int i = tid; i < N_EDGES; i += stride) {
        int src, dst;
        if (flag) {
            src = i32[i];
            dst = i32[N_EDGES + i];
        } else {
            src = (int)i64[i];
            dst = (int)i64[N_EDGES + i];
        }
        const float2 ep = params[i];
        const float  lg = logits[i];
        const float  vs = nf[src * 4];
        const float  vd = nf[dst * 4];

        const float p   = 1.0f / (1.0f + __expf(-lg));
        const float cur = fabsf(vs - vd) / (ep.x + ep.y + EPS_F) * p;

        atomicAdd(node_sum + dst,  cur);
        atomicAdd(node_sum + src, -cur);

        s0 += ep.x; s1 += ep.y;
        q0 += ep.x * ep.x; q1 += ep.y * ep.y;
    }

    s0 = wave_reduce(s0);
    s1 = wave_reduce(s1);
    q0 = wave_reduce(q0);
    q1 = wave_reduce(q1);
    if ((threadIdx.x & 63) == 0) {
        atomicAdd(acc + 0, s0);
        atomicAdd(acc + 1, s1);
        atomicAdd(acc + 2, q0);
        atomicAdd(acc + 3, q1);
    }
}

__global__ __launch_bounds__(256) void kcl_kernel(float* __restrict__ ws) {
    const float* node_sum = ws + WS_NODE_OFF;
    float acc = 0.f;
    const int tid    = blockIdx.x * blockDim.x + threadIdx.x;
    const int stride = gridDim.x * blockDim.x;
    for (int i = tid; i < N_NODES; i += stride) {
        const float v = node_sum[i];
        acc += v * v;
    }
    acc = wave_reduce(acc);
    if ((threadIdx.x & 63) == 0) atomicAdd(ws + 5, acc);
}

__global__ void final_kernel(const float* __restrict__ ws, float* __restrict__ out) {
    const float s0 = ws[1], s1 = ws[2], q0 = ws[3], q1 = ws[4], k = ws[5];
    const float n  = (float)N_EDGES;
    const float var0 = (q0 - s0 * s0 / n) / (n - 1.0f);
    const float var1 = (q1 - s1 * s1 / n) / (n - 1.0f);
    out[0] = k / (float)N_NODES + 0.5f * (var0 + var1);
}

extern "C" void kernel_launch(void* const* d_in, const int* in_sizes, int n_in,
                              void* d_out, int out_size, void* d_ws, size_t ws_size,
                              hipStream_t stream) {
    const float*  nf     = (const float*)d_in[0];
    const void*   eidx   = d_in[1];
    const float*  logits = (const float*)d_in[2];
    const float2* params = (const float2*)d_in[3];
    float* ws  = (float*)d_ws;
    float* out = (float*)d_out;

    // Zero flag + accumulators + node_sum (ws is re-poisoned to 0xAA each call).
    hipMemsetAsync(d_ws, 0, WS_ZERO_BYTES, stream);

    detect_idx_kernel<<<1, 64, 0, stream>>>((const int*)eidx, (int*)d_ws);

    // 2048 blocks x 256 threads = 8192 waves = full-chip wave capacity.
    edge_kernel<<<2048, 256, 0, stream>>>(nf, eidx, logits, params, ws);

    kcl_kernel<<<200, 256, 0, stream>>>(ws);

    final_kernel<<<1, 1, 0, stream>>>(ws, out);
}

// Round 2
// 674.037 us; speedup vs baseline: 1.0030x; 1.0030x over previous
//
#include <hip/hip_runtime.h>
#include <math.h>

#define N_NODES 100000
#define N_EDGES 3200000
#define EPS_F 1e-6f

// ws layout (floats):
//   [0]  : int flag (1 = edge_index is int32, 0 = int64)
//   [1]  : sum(p0)      [2] : sum(p1)
//   [3]  : sum(p0^2)    [4] : sum(p1^2)
//   [5]  : sum(node_sum^2)
//   [64..64+N_NODES) : node_sum (byte offset 256)
#define WS_NODE_OFF 64
#define WS_ZERO_BYTES (256 + N_NODES * sizeof(float))

__global__ void detect_idx_kernel(const int* __restrict__ idx, int* __restrict__ flag) {
    if (threadIdx.x == 0 && blockIdx.x == 0) {
        int any = 0;
        // int64 layout (values < 2^31): every odd 32-bit word is zero.
        // int32 layout: odd words are random node ids (16 zeros ~ impossible).
        #pragma unroll
        for (int k = 1; k < 32; k += 2) any |= idx[k];
        *flag = (any != 0) ? 1 : 0;
    }
}

__device__ __forceinline__ float wave_reduce(float v) {
    #pragma unroll
    for (int off = 32; off > 0; off >>= 1) v += __shfl_down(v, off, 64);
    return v;
}

// Native fire-and-forget fp32 global atomic add (no CAS loop, no return).
__device__ __forceinline__ void fadd_native(float* p, float v) {
#if defined(__AMDGCN__)
    unsafeAtomicAdd(p, v);
#else
    atomicAdd(p, v);
#endif
}

__global__ __launch_bounds__(256) void edge_kernel(
    const float*  __restrict__ nf,      // node_features [N_NODES,4]
    const void*   __restrict__ eidx,    // edge_index [2, N_EDGES], int32 or int64
    const float*  __restrict__ logits,  // [N_EDGES]
    const float2* __restrict__ params,  // [N_EDGES, 2]
    float*        __restrict__ ws)
{
    const int flag = ((const int*)ws)[0];
    float* node_sum = ws + WS_NODE_OFF;
    float* acc = ws + 1;
    const int*       i32 = (const int*)eidx;
    const long long* i64 = (const long long*)eidx;

    float s0 = 0.f, s1 = 0.f, q0 = 0.f, q1 = 0.f;
    const int tid    = blockIdx.x * blockDim.x + threadIdx.x;
    const int stride = gridDim.x * blockDim.x;

    for (int i = tid; i < N_EDGES; i += stride) {
        int src, dst;
        if (flag) {
            src = i32[i];
            dst = i32[N_EDGES + i];
        } else {
            src = (int)i64[i];
            dst = (int)i64[N_EDGES + i];
        }
        const float2 ep = params[i];
        const float  lg = logits[i];
        const float  vs = nf[src * 4];
        const float  vd = nf[dst * 4];

        const float p   = 1.0f / (1.0f + __expf(-lg));
        const float cur = fabsf(vs - vd) / (ep.x + ep.y + EPS_F) * p;

        fadd_native(node_sum + dst,  cur);
        fadd_native(node_sum + src, -cur);

        s0 += ep.x; s1 += ep.y;
        q0 += ep.x * ep.x; q1 += ep.y * ep.y;
    }

    s0 = wave_reduce(s0);
    s1 = wave_reduce(s1);
    q0 = wave_reduce(q0);
    q1 = wave_reduce(q1);
    if ((threadIdx.x & 63) == 0) {
        fadd_native(acc + 0, s0);
        fadd_native(acc + 1, s1);
        fadd_native(acc + 2, q0);
        fadd_native(acc + 3, q1);
    }
}

__global__ __launch_bounds__(256) void kcl_kernel(float* __restrict__ ws) {
    const float* node_sum = ws + WS_NODE_OFF;
    float acc = 0.f;
    const int tid    = blockIdx.x * blockDim.x + threadIdx.x;
    const int stride = gridDim.x * blockDim.x;
    for (int i = tid; i < N_NODES; i += stride) {
        const float v = node_sum[i];
        acc += v * v;
    }
    acc = wave_reduce(acc);
    if ((threadIdx.x & 63) == 0) fadd_native(ws + 5, acc);
}

__global__ void final_kernel(const float* __restrict__ ws, float* __restrict__ out) {
    const float s0 = ws[1], s1 = ws[2], q0 = ws[3], q1 = ws[4], k = ws[5];
    const float n  = (float)N_EDGES;
    const float var0 = (q0 - s0 * s0 / n) / (n - 1.0f);
    const float var1 = (q1 - s1 * s1 / n) / (n - 1.0f);
    out[0] = k / (float)N_NODES + 0.5f * (var0 + var1);
}

extern "C" void kernel_launch(void* const* d_in, const int* in_sizes, int n_in,
                              void* d_out, int out_size, void* d_ws, size_t ws_size,
                              hipStream_t stream) {
    const float*  nf     = (const float*)d_in[0];
    const void*   eidx   = d_in[1];
    const float*  logits = (const float*)d_in[2];
    const float2* params = (const float2*)d_in[3];
    float* ws  = (float*)d_ws;
    float* out = (float*)d_out;

    hipMemsetAsync(d_ws, 0, WS_ZERO_BYTES, stream);

    detect_idx_kernel<<<1, 64, 0, stream>>>((const int*)eidx, (int*)d_ws);

    edge_kernel<<<2048, 256, 0, stream>>>(nf, eidx, logits, params, ws);

    kcl_kernel<<<200, 256, 0, stream>>>(ws);

    final_kernel<<<1, 1, 0, stream>>>(ws, out);
}